// Round 2
// baseline (15.845 us; speedup 1.0000x reference)
//
#include <hip/hip_runtime.h>

// EmbeddingShardV2: out[b,s,:] = W[x[b,s],:] + bias
// x: [4,2048] int32, W: [50304,1024] f32, b: [1024] f32, out: [4,2048,1024] f32
//
// R1: 1 token/block -> dependent {idx load -> row load -> store} chain, ILP=1,
// 4.2 TB/s effective. R2: 4 tokens/block; indices loaded up front, 4
// independent float4 gathers in flight per thread, bias loaded once and
// reused. 2048 blocks x 256 threads = 8 blocks/CU x 4 waves (full occupancy).

constexpr int D4  = 1024 / 4;  // float4s per row = 256
constexpr int TPB = 4;         // tokens per block

__global__ __launch_bounds__(256)
void embed_gather4_kernel(const int* __restrict__ x,
                          const float4* __restrict__ W,
                          const float4* __restrict__ bias,
                          float4* __restrict__ out,
                          int n_tok) {
    const int t0 = blockIdx.x * TPB;
    const int i  = threadIdx.x;          // 0..255 == D4

    // Indices first — all 4 issued before any dependent use.
    int r0 = x[t0 + 0];
    int r1 = x[t0 + 1];
    int r2 = x[t0 + 2];
    int r3 = x[t0 + 3];

    float4 bb = bias[i];                 // L1/L2-resident after first blocks

    // 4 independent gathers in flight per thread.
    float4 w0 = W[(size_t)r0 * D4 + i];
    float4 w1 = W[(size_t)r1 * D4 + i];
    float4 w2 = W[(size_t)r2 * D4 + i];
    float4 w3 = W[(size_t)r3 * D4 + i];

    w0.x += bb.x; w0.y += bb.y; w0.z += bb.z; w0.w += bb.w;
    w1.x += bb.x; w1.y += bb.y; w1.z += bb.z; w1.w += bb.w;
    w2.x += bb.x; w2.y += bb.y; w2.z += bb.z; w2.w += bb.w;
    w3.x += bb.x; w3.y += bb.y; w3.z += bb.z; w3.w += bb.w;

    float4* __restrict__ dst = out + (size_t)t0 * D4 + i;
    dst[0 * D4] = w0;
    dst[1 * D4] = w1;
    dst[2 * D4] = w2;
    dst[3 * D4] = w3;
}

extern "C" void kernel_launch(void* const* d_in, const int* in_sizes, int n_in,
                              void* d_out, int out_size, void* d_ws, size_t ws_size,
                              hipStream_t stream) {
    const int*    x    = (const int*)d_in[0];     // [B*S] = 8192
    const float4* W    = (const float4*)d_in[1];  // [50304,1024] f32
    const float4* bias = (const float4*)d_in[2];  // [1024] f32
    float4*       out  = (float4*)d_out;          // [B*S,1024] f32

    const int n_tok = in_sizes[0];                // 8192 (multiple of TPB)
    embed_gather4_kernel<<<n_tok / TPB, 256, 0, stream>>>(x, W, bias, out, n_tok);
}

// Round 4
// 14.143 us; speedup vs baseline: 1.1203x; 1.1203x over previous
//
#include <hip/hip_runtime.h>

// EmbeddingShardV2: out[b,s,:] = W[x[b,s],:] + bias
// x: [4,2048] int32, W: [50304,1024] f32, b: [1024] f32, out: [4,2048,1024] f32
//
// R1 (1 tok/block) and R2 (4 tok/block, 4-deep MLP) both 15.84 us -> at a
// floor, not latency-bound. R3/R4: non-temporal stores for out (write-once,
// never re-read) so the 33.5 MB output stream doesn't evict W (206 MB, fits
// in 256 MB Infinity Cache). R4 fixes R3's compile error: the builtin needs a
// native clang vector type, not HIP_vector_type<float,4>.

typedef float f32x4 __attribute__((ext_vector_type(4)));

constexpr int D4  = 1024 / 4;  // float4s per row = 256
constexpr int TPB = 4;         // tokens per block

__global__ __launch_bounds__(256)
void embed_gather_nt_kernel(const int* __restrict__ x,
                            const f32x4* __restrict__ W,
                            const f32x4* __restrict__ bias,
                            f32x4* __restrict__ out,
                            int n_tok) {
    const int t0 = blockIdx.x * TPB;
    const int i  = threadIdx.x;          // 0..255 == D4

    int r0 = x[t0 + 0];
    int r1 = x[t0 + 1];
    int r2 = x[t0 + 2];
    int r3 = x[t0 + 3];

    f32x4 bb = bias[i];

    f32x4 w0 = W[(size_t)r0 * D4 + i];
    f32x4 w1 = W[(size_t)r1 * D4 + i];
    f32x4 w2 = W[(size_t)r2 * D4 + i];
    f32x4 w3 = W[(size_t)r3 * D4 + i];

    w0 += bb;
    w1 += bb;
    w2 += bb;
    w3 += bb;

    f32x4* __restrict__ dst = out + (size_t)t0 * D4 + i;
    __builtin_nontemporal_store(w0, &dst[0 * D4]);
    __builtin_nontemporal_store(w1, &dst[1 * D4]);
    __builtin_nontemporal_store(w2, &dst[2 * D4]);
    __builtin_nontemporal_store(w3, &dst[3 * D4]);
}

extern "C" void kernel_launch(void* const* d_in, const int* in_sizes, int n_in,
                              void* d_out, int out_size, void* d_ws, size_t ws_size,
                              hipStream_t stream) {
    const int*   x    = (const int*)d_in[0];     // [B*S] = 8192
    const f32x4* W    = (const f32x4*)d_in[1];   // [50304,1024] f32
    const f32x4* bias = (const f32x4*)d_in[2];   // [1024] f32
    f32x4*       out  = (f32x4*)d_out;           // [B*S,1024] f32

    const int n_tok = in_sizes[0];               // 8192 (multiple of TPB)
    embed_gather_nt_kernel<<<n_tok / TPB, 256, 0, stream>>>(x, W, bias, out, n_tok);
}